// Round 7
// baseline (172.116 us; speedup 1.0000x reference)
//
#include <hip/hip_runtime.h>
#include <stdint.h>

#define N_NODES 50000
#define N_EDGES 1600000
#define N_FEAT 128
#define CAP 64            // final slots per row; Poisson(28.8) mean, +6.5 sigma
#define OVF_PW 256        // per-partA-wg overflow slots (expected usage: 0)
#define OVF_PB 192        // per-partB-bucket overflow slots (expected usage: 0)

// radix-partition parameters
#define RSHIFT 8          // 256 rows per coarse bucket
#define BROWS 256
#define NB 196            // ceil(50000 / 256)
#define NWG_A 250         // pass-A workgroups; 250*1600 chunks * 4 edges = 1.6M exact
#define A_THREADS 1024
#define CHUNKS_PW 1600    // 4-edge chunks per pass-A wg
#define CAPW 56           // slots per (bucket, wg) segment; mean 29.4, ~+4.9 sigma
#define NREG (NWG_A + NB) // 446 overflow regions total

// ---------------- threefry2x32 (bit-exact, KAT-verified vs Random123) ----------

struct KeyPair { uint32_t a, b; };

__host__ __device__ constexpr inline uint32_t rotl32(uint32_t x, int r) {
  return (x << r) | (x >> (32 - r));
}

__host__ __device__ constexpr inline KeyPair threefry2x32(uint32_t k0, uint32_t k1,
                                                          uint32_t x0, uint32_t x1) {
  const uint32_t ks0 = k0, ks1 = k1, ks2 = k0 ^ k1 ^ 0x1BD11BDAu;
  x0 += ks0;
  x1 += ks1;
  const int rotA[4] = {13, 15, 26, 6};
  const int rotB[4] = {17, 29, 16, 24};
  const uint32_t ks[3] = {ks0, ks1, ks2};
  for (int i = 0; i < 5; ++i) {
    const int* rot = (i & 1) ? rotB : rotA;
    for (int j = 0; j < 4; ++j) {
      x0 += x1;
      x1 = rotl32(x1, rot[j]);
      x1 ^= x0;
    }
    x0 += ks[(i + 1) % 3];
    x1 += ks[(i + 2) % 3] + (uint32_t)(i + 1);
  }
  return {x0, x1};
}

// mask_key = fold_in(key(42), 7); compile-time.
constexpr KeyPair MASK_KEY = threefry2x32(0u, 42u, 0u, 7u);

// Partitionable (counter-mode) random_bits: element i -> threefry(key, (0, i)), bits = b1^b2.
__device__ inline bool edge_keep(uint32_t e) {
  KeyPair r = threefry2x32(MASK_KEY.a, MASK_KEY.b, 0u, e);
  uint32_t bits = r.a ^ r.b;
  float u = __uint_as_float((bits >> 9) | 0x3f800000u) - 1.0f;
  return u < 0.9f;
}

// fp32 bits -> bf16 with round-to-nearest-even
__device__ inline uint32_t f2bf(uint32_t b) {
  return (b + 0x7fffu + ((b >> 16) & 1u)) >> 16;
}

// true vector types (ext_vector_type) -- __builtin_nontemporal_* rejects HIP's
// class-type uint2/float4, but accepts these (identical layout & codegen).
typedef uint32_t u4v __attribute__((ext_vector_type(4)));
typedef float f4v __attribute__((ext_vector_type(4)));

// =================== PRIMARY PATH ==============================================
// coarse pack: (row << 48) | (col << 32) | f32bits(val)
// final payload (u32): (col << 16) | bf16bits(val); cursor[r] = exact count.
//
// NT policy (round-4 post-mortem): xb/coarse/payload are producer->consumer
// buffers -- CACHED stores so they land in LLC at kernel end. NT only for:
// payload loads in gather (read-once) and out stores (write-once, never read).

// x -> bf16 conversion, standalone pure-BW kernel (split from pass A for
// rocprof visibility and to decouple its stragglers from the binning phase).
// 38.4 MB moved; expected ~7-9us.
__global__ void __launch_bounds__(256) conv_bf16_kernel(const float* __restrict__ x,
                                                        uint32_t* __restrict__ xb) {
  const int T = (int)gridDim.x * 256;
  for (int i = blockIdx.x * 256 + threadIdx.x; i < (N_NODES * N_FEAT) / 8; i += T) {
    f4v a = ((const f4v*)x)[2 * i];
    f4v b = ((const f4v*)x)[2 * i + 1];
    u4v o;
    o.x = f2bf(__float_as_uint(a.x)) | (f2bf(__float_as_uint(a.y)) << 16);
    o.y = f2bf(__float_as_uint(a.z)) | (f2bf(__float_as_uint(a.w)) << 16);
    o.z = f2bf(__float_as_uint(b.x)) | (f2bf(__float_as_uint(b.y)) << 16);
    o.w = f2bf(__float_as_uint(b.z)) | (f2bf(__float_as_uint(b.w)) << 16);
    ((u4v*)xb)[i] = o;
  }
}

// Pass A: per-wg compaction into (bucket, wg) segments using LDS counters only
// (round-2 post-mortem: global atomics cost ~100MB HBM write traffic +
// serialize at HBM latency). Per-wg overflow region (count written
// unconditionally) -> no host-side memset dispatch needed.
__global__ void __launch_bounds__(A_THREADS) partA_bin_kernel(const float* __restrict__ adj_vals,
                                                              const int* __restrict__ row,
                                                              const int* __restrict__ col,
                                                              uint64_t* __restrict__ coarse,
                                                              uint32_t* __restrict__ lens,
                                                              uint32_t* __restrict__ ovfcA,
                                                              uint64_t* __restrict__ ovfA) {
  __shared__ uint32_t cnt[NB];
  __shared__ uint32_t ovfc;
  int wg = blockIdx.x;
  int tid = threadIdx.x;
  if (tid < NB) cnt[tid] = 0;
  if (tid == 0) ovfc = 0;
  __syncthreads();  // cnt/ovfc init visible

  // bin 4-edge chunks (vector loads), LDS-atomic slot ranks
  for (int ch = tid; ch < CHUNKS_PW; ch += A_THREADS) {
    const int g = wg * CHUNKS_PW + ch;     // global chunk; edges [4g, 4g+4)
    const int4 r4 = ((const int4*)row)[g];
    const int4 c4 = ((const int4*)col)[g];
    const float4 a4 = ((const float4*)adj_vals)[g];
    const int rr[4] = {r4.x, r4.y, r4.z, r4.w};
    const int cc[4] = {c4.x, c4.y, c4.z, c4.w};
    const float aa[4] = {a4.x, a4.y, a4.z, a4.w};
#pragma unroll
    for (int k = 0; k < 4; ++k) {
      const uint32_t e = (uint32_t)(4 * g + k);
      if (!edge_keep(e)) continue;
      const uint32_t r = (uint32_t)rr[k];
      const uint32_t c = (uint32_t)cc[k];
      const float v = aa[k] / 0.9f;
      const uint32_t b = r >> RSHIFT;
      const uint32_t li = atomicAdd(&cnt[b], 1u);
      const uint64_t p = ((uint64_t)r << 48) | ((uint64_t)c << 32) | (uint64_t)__float_as_uint(v);
      if (li < CAPW) {
        coarse[((size_t)b * NWG_A + wg) * CAPW + li] = p;
      } else {
        const uint32_t oi = atomicAdd(&ovfc, 1u);
        if (oi < OVF_PW) ovfA[(size_t)wg * OVF_PW + oi] = p;
      }
    }
  }
  __syncthreads();
  if (tid < NB) lens[(size_t)tid * NWG_A + wg] = min(cnt[tid], (uint32_t)CAPW);
  if (tid == 0) ovfcA[wg] = min(ovfc, (uint32_t)OVF_PW);
}

// Pass B: one 1024-thread wg per 256-row bucket. Segment lengths prefetched to
// LDS. HALF-WAVE (32-lane) per segment: mean len is 29.4, so a full wave had
// ~29/64 lanes active and 15.6 dependent {load->atomic->store} iterations; two
// segments per wave doubles active lanes and halves the chain count. Inner
// stride-32 loop covers the ~27% of segments with len>32. Rows padded with
// zero-words to a multiple of 8 so the gather needs no masking.
__global__ void __launch_bounds__(1024) partB_kernel(const uint64_t* __restrict__ coarse,
                                                     const uint32_t* __restrict__ lens,
                                                     uint32_t* __restrict__ payload,
                                                     uint32_t* __restrict__ cursor,
                                                     uint32_t* __restrict__ ovfcB,
                                                     uint64_t* __restrict__ ovfB) {
  int b = blockIdx.x;
  int tid = threadIdx.x;
  __shared__ uint32_t cnt[BROWS];   // per local-row fill count
  __shared__ uint32_t s_len[NWG_A];
  __shared__ uint32_t ovfc;
  if (tid < BROWS) cnt[tid] = 0;
  if (tid < NWG_A) s_len[tid] = lens[(size_t)b * NWG_A + tid];
  if (tid == 0) ovfc = 0;
  __syncthreads();

  int hw = tid >> 5;     // 32 half-waves
  int lane = tid & 31;
  for (int seg = hw; seg < NWG_A; seg += 32) {
    uint32_t len = s_len[seg];   // half-wave-uniform, LDS
    const uint64_t* cseg = coarse + ((size_t)b * NWG_A + seg) * CAPW;
    for (uint32_t li = (uint32_t)lane; li < len; li += 32) {
      uint64_t p = cseg[li];
      uint32_t r = (uint32_t)(p >> 48);
      uint32_t rl = r & (BROWS - 1);
      uint32_t idx = atomicAdd(&cnt[rl], 1u);
      if (idx < CAP) {
        uint32_t c = (uint32_t)(p >> 32) & 0xFFFFu;
        payload[(size_t)r * CAP + idx] = (c << 16) | f2bf((uint32_t)p);
      } else {
        uint32_t oi = atomicAdd(&ovfc, 1u);
        if (oi < OVF_PB) ovfB[(size_t)b * OVF_PB + oi] = p;
      }
    }
  }
  __syncthreads();
  // exact count to cursor; zero-pad slots to a multiple of 8
  if (tid < BROWS) {
    uint32_t r = ((uint32_t)b << RSHIFT) + (uint32_t)tid;
    if (r < N_NODES) {
      uint32_t c0 = min(cnt[tid], (uint32_t)CAP);
      cursor[r] = c0;
      uint32_t np = min((c0 + 7u) & ~7u, (uint32_t)CAP);
      for (uint32_t i2 = c0; i2 < np; ++i2) payload[(size_t)r * CAP + i2] = 0u;
    }
  }
  if (tid == 0) ovfcB[b] = min(ovfc, (uint32_t)OVF_PB);
}

// Gather from bf16 x: 16-lane teams per row (dwordx4 = 8 feats/lane), 16 teams
// per 256-thread block. ROUND-1 PROVEN FORM (43us): padded slot count, no
// register masking, and ALL payload chunks preloaded BEFORE the compute chain
// (rounds 4/5 post-mortem: lazy mid-loop p2/p3 loads serialize an un-overlapped
// LLC round-trip for the ~35% of rows with >32 edges -- cost ~4us).
__global__ void __launch_bounds__(256) gather_bf16_kernel(const uint32_t* __restrict__ xb,
                                                          const uint32_t* __restrict__ payload,
                                                          const uint32_t* __restrict__ cursor,
                                                          float* __restrict__ out) {
  int r = blockIdx.x * 16 + (threadIdx.x >> 4);
  int lane = threadIdx.x & 15;
  uint32_t base = (uint32_t)r * CAP;
  uint32_t cnt = cursor[r];                   // exact count, <= CAP
  uint32_t n = (cnt + 7u) & ~7u;              // padded count; pads are zeros
  const uint4* x4 = (const uint4*)xb;         // row stride: 16 uint4 (128 bf16)

  float acc0 = 0.f, acc1 = 0.f, acc2 = 0.f, acc3 = 0.f;
  float acc4 = 0.f, acc5 = 0.f, acc6 = 0.f, acc7 = 0.f;

  // preload ALL payload chunks this row needs (coalesced 64B per team, NT)
  uint32_t p0 = __builtin_nontemporal_load(payload + base + lane);
  uint32_t p1 = __builtin_nontemporal_load(payload + base + 16 + lane);
  uint32_t p2 = (n > 32u) ? __builtin_nontemporal_load(payload + base + 32 + lane) : 0u;
  uint32_t p3 = (n > 48u) ? __builtin_nontemporal_load(payload + base + 48 + lane) : 0u;

#define GSTEP(ww)                                                            \
  {                                                                          \
    uint32_t cc = (ww) >> 16;                                                \
    float vv = __uint_as_float((ww) << 16);                                  \
    uint4 a = x4[(size_t)cc * 16 + lane];                                    \
    acc0 += vv * __uint_as_float(a.x << 16);                                 \
    acc1 += vv * __uint_as_float(a.x & 0xffff0000u);                         \
    acc2 += vv * __uint_as_float(a.y << 16);                                 \
    acc3 += vv * __uint_as_float(a.y & 0xffff0000u);                         \
    acc4 += vv * __uint_as_float(a.z << 16);                                 \
    acc5 += vv * __uint_as_float(a.z & 0xffff0000u);                         \
    acc6 += vv * __uint_as_float(a.w << 16);                                 \
    acc7 += vv * __uint_as_float(a.w & 0xffff0000u);                         \
  }

#define PCHUNK(preg, mm)                                                     \
  for (int j = 0; j < (mm); j += 8) {                                        \
    uint32_t w0 = __shfl((preg), j + 0, 16);                                 \
    uint32_t w1 = __shfl((preg), j + 1, 16);                                 \
    uint32_t w2 = __shfl((preg), j + 2, 16);                                 \
    uint32_t w3 = __shfl((preg), j + 3, 16);                                 \
    uint32_t w4 = __shfl((preg), j + 4, 16);                                 \
    uint32_t w5 = __shfl((preg), j + 5, 16);                                 \
    uint32_t w6 = __shfl((preg), j + 6, 16);                                 \
    uint32_t w7 = __shfl((preg), j + 7, 16);                                 \
    GSTEP(w0) GSTEP(w1) GSTEP(w2) GSTEP(w3)                                  \
    GSTEP(w4) GSTEP(w5) GSTEP(w6) GSTEP(w7)                                  \
  }

  int rem = (int)n;   // multiple of 8
  PCHUNK(p0, min(rem, 16));
  rem -= 16;
  if (rem > 0) {
    PCHUNK(p1, min(rem, 16));
    rem -= 16;
    if (rem > 0) {
      PCHUNK(p2, min(rem, 16));
      rem -= 16;
      if (rem > 0) {
        PCHUNK(p3, min(rem, 16));
      }
    }
  }
#undef PCHUNK
#undef GSTEP

  // lane stores feats 8*lane .. 8*lane+7 -> 512B contiguous per team (NT)
  f4v lo, hi;
  lo.x = acc0; lo.y = acc1; lo.z = acc2; lo.w = acc3;
  hi.x = acc4; hi.y = acc5; hi.z = acc6; hi.w = acc7;
  f4v* o = (f4v*)out + (size_t)r * 32 + lane * 2;
  __builtin_nontemporal_store(lo, o);
  __builtin_nontemporal_store(hi, o + 1);
}

// exact cleanup for packed (row,col,f32val) overflow entries. Early-exits when
// all 446 region counts are zero (the expected case).
__global__ void __launch_bounds__(256) ovf_pack_kernel(const float* __restrict__ x,
                                                       const uint32_t* __restrict__ ovfcA,
                                                       const uint64_t* __restrict__ ovfA,
                                                       const uint32_t* __restrict__ ovfcB,
                                                       const uint64_t* __restrict__ ovfB,
                                                       float* __restrict__ out) {
  __shared__ int any;
  if (threadIdx.x == 0) any = 0;
  __syncthreads();
  for (int t = threadIdx.x; t < NREG; t += 256) {
    uint32_t c = (t < NWG_A) ? ovfcA[t] : ovfcB[t - NWG_A];
    if (c) any = 1;
  }
  __syncthreads();
  if (!any) return;

  int group = (int)((blockIdx.x * 256 + threadIdx.x) >> 7);
  int f = threadIdx.x & 127;
  const int ngroups = (16 * 256) >> 7;  // 32 groups
  for (int reg = group; reg < NREG; reg += ngroups) {
    uint32_t c;
    const uint64_t* basep;
    if (reg < NWG_A) {
      c = min(ovfcA[reg], (uint32_t)OVF_PW);
      basep = ovfA + (size_t)reg * OVF_PW;
    } else {
      c = min(ovfcB[reg - NWG_A], (uint32_t)OVF_PB);
      basep = ovfB + (size_t)(reg - NWG_A) * OVF_PB;
    }
    for (uint32_t i = 0; i < c; ++i) {
      uint64_t p = basep[i];
      uint32_t r = (uint32_t)(p >> 48);
      uint32_t cc = (uint32_t)((p >> 32) & 0xFFFFu);
      float v = __uint_as_float((uint32_t)p);
      atomicAdd(&out[(size_t)r * N_FEAT + f], v * x[(size_t)cc * N_FEAT + f]);
    }
  }
}

// =================== FALLBACK: fused atomic scatter ============================

__global__ void __launch_bounds__(256) scatter_fused_kernel(const float* __restrict__ x,
                                                            const float* __restrict__ adj_vals,
                                                            const int* __restrict__ row,
                                                            const int* __restrict__ col,
                                                            float* __restrict__ out) {
  long long t = (long long)blockIdx.x * blockDim.x + threadIdx.x;
  int e = (int)(t >> 6);
  int lane = (int)(t & 63);
  if (e >= N_EDGES) return;
  if (!edge_keep((uint32_t)e)) return;
  float v = adj_vals[e] / 0.9f;
  float2 xf = *(const float2*)(x + (long long)col[e] * N_FEAT + lane * 2);
  float* dst = out + (long long)row[e] * N_FEAT + lane * 2;
  atomicAdd(dst, v * xf.x);
  atomicAdd(dst + 1, v * xf.y);
}

// ---------------- launch --------------------------------------------------------

extern "C" void kernel_launch(void* const* d_in, const int* in_sizes, int n_in,
                              void* d_out, int out_size, void* d_ws, size_t ws_size,
                              hipStream_t stream) {
  const float* x        = (const float*)d_in[0];
  const float* adj_vals = (const float*)d_in[1];
  const int*   row      = (const int*)d_in[2];
  const int*   col      = (const int*)d_in[3];
  float* out = (float*)d_out;

  // ---- workspace layout (nothing needs host-side init) ----
  size_t a_cursor  = 0;                                                    // N u32
  size_t a_ovfcA   = (a_cursor + (size_t)N_NODES * 4 + 255) & ~255ull;     // NWG_A u32
  size_t a_ovfcB   = (a_ovfcA + (size_t)NWG_A * 4 + 255) & ~255ull;        // NB u32
  size_t a_lens    = (a_ovfcB + (size_t)NB * 4 + 255) & ~255ull;           // NB*NWG_A u32
  size_t a_ovfA    = (a_lens + (size_t)NB * NWG_A * 4 + 255) & ~255ull;    // NWG_A*OVF_PW u64
  size_t a_ovfB    = (a_ovfA + (size_t)NWG_A * OVF_PW * 8 + 255) & ~255ull; // NB*OVF_PB u64
  size_t a_coarse  = (a_ovfB + (size_t)NB * OVF_PB * 8 + 255) & ~255ull;   // NB*NWG_A*CAPW u64
  size_t a_payload = (a_coarse + (size_t)NB * NWG_A * CAPW * 8 + 255) & ~255ull;  // N*CAP u32
  size_t a_xb      = (a_payload + (size_t)N_NODES * CAP * 4 + 255) & ~255ull;     // N*F bf16
  size_t need      = a_xb + (size_t)N_NODES * N_FEAT * 2;

  if (ws_size >= need) {
    uint32_t* cursor  = (uint32_t*)((char*)d_ws + a_cursor);
    uint32_t* ovfcA   = (uint32_t*)((char*)d_ws + a_ovfcA);
    uint32_t* ovfcB   = (uint32_t*)((char*)d_ws + a_ovfcB);
    uint32_t* lens    = (uint32_t*)((char*)d_ws + a_lens);
    uint64_t* ovfA    = (uint64_t*)((char*)d_ws + a_ovfA);
    uint64_t* ovfB    = (uint64_t*)((char*)d_ws + a_ovfB);
    uint64_t* coarse  = (uint64_t*)((char*)d_ws + a_coarse);
    uint32_t* payload = (uint32_t*)((char*)d_ws + a_payload);
    uint32_t* xb      = (uint32_t*)((char*)d_ws + a_xb);

    conv_bf16_kernel<<<1024, 256, 0, stream>>>(x, xb);
    partA_bin_kernel<<<NWG_A, A_THREADS, 0, stream>>>(adj_vals, row, col,
                                                      coarse, lens, ovfcA, ovfA);
    partB_kernel<<<NB, 1024, 0, stream>>>(coarse, lens, payload, cursor, ovfcB, ovfB);
    gather_bf16_kernel<<<N_NODES / 16, 256, 0, stream>>>(xb, payload, cursor, out);
    ovf_pack_kernel<<<16, 256, 0, stream>>>(x, ovfcA, ovfA, ovfcB, ovfB, out);
  } else {
    hipMemsetAsync(d_out, 0, (size_t)out_size * sizeof(float), stream);
    long long total_threads = (long long)N_EDGES * 64;
    scatter_fused_kernel<<<(int)((total_threads + 255) / 256), 256, 0, stream>>>(
        x, adj_vals, row, col, out);
  }
}

// Round 8
// 163.411 us; speedup vs baseline: 1.0533x; 1.0533x over previous
//
#include <hip/hip_runtime.h>
#include <stdint.h>

#define N_NODES 50000
#define N_EDGES 1600000
#define N_FEAT 128
#define CAP 64            // final slots per row; Poisson(28.8) mean, +6.5 sigma
#define OVF_PW 256        // per-convA-wg overflow slots (expected usage: 0)
#define OVF_PB 192        // per-partB-bucket overflow slots (expected usage: 0)

// radix-partition parameters
#define RSHIFT 8          // 256 rows per coarse bucket
#define BROWS 256
#define NB 196            // ceil(50000 / 256)
#define NWG_A 250         // pass-A workgroups; 250*1600 chunks * 4 edges = 1.6M exact
#define A_THREADS 1024
#define CHUNKS_PW 1600    // 4-edge chunks per pass-A wg
#define CAPW 56           // slots per (bucket, wg) segment; mean 29.4, ~+4.9 sigma
#define NREG (NWG_A + NB) // 446 overflow regions total

// ---------------- threefry2x32 (bit-exact, KAT-verified vs Random123) ----------

struct KeyPair { uint32_t a, b; };

__host__ __device__ constexpr inline uint32_t rotl32(uint32_t x, int r) {
  return (x << r) | (x >> (32 - r));
}

__host__ __device__ constexpr inline KeyPair threefry2x32(uint32_t k0, uint32_t k1,
                                                          uint32_t x0, uint32_t x1) {
  const uint32_t ks0 = k0, ks1 = k1, ks2 = k0 ^ k1 ^ 0x1BD11BDAu;
  x0 += ks0;
  x1 += ks1;
  const int rotA[4] = {13, 15, 26, 6};
  const int rotB[4] = {17, 29, 16, 24};
  const uint32_t ks[3] = {ks0, ks1, ks2};
  for (int i = 0; i < 5; ++i) {
    const int* rot = (i & 1) ? rotB : rotA;
    for (int j = 0; j < 4; ++j) {
      x0 += x1;
      x1 = rotl32(x1, rot[j]);
      x1 ^= x0;
    }
    x0 += ks[(i + 1) % 3];
    x1 += ks[(i + 2) % 3] + (uint32_t)(i + 1);
  }
  return {x0, x1};
}

// mask_key = fold_in(key(42), 7); compile-time.
constexpr KeyPair MASK_KEY = threefry2x32(0u, 42u, 0u, 7u);

// Partitionable (counter-mode) random_bits: element i -> threefry(key, (0, i)), bits = b1^b2.
__device__ inline bool edge_keep(uint32_t e) {
  KeyPair r = threefry2x32(MASK_KEY.a, MASK_KEY.b, 0u, e);
  uint32_t bits = r.a ^ r.b;
  float u = __uint_as_float((bits >> 9) | 0x3f800000u) - 1.0f;
  return u < 0.9f;
}

// fp32 bits -> bf16 with round-to-nearest-even
__device__ inline uint32_t f2bf(uint32_t b) {
  return (b + 0x7fffu + ((b >> 16) & 1u)) >> 16;
}

// true vector types (ext_vector_type) -- __builtin_nontemporal_* rejects HIP's
// class-type uint2/float4, but accepts these (identical layout & codegen).
typedef uint32_t u4v __attribute__((ext_vector_type(4)));
typedef float f4v __attribute__((ext_vector_type(4)));

// =================== PRIMARY PATH ==============================================
// coarse pack: (row << 48) | (col << 32) | f32bits(val)
// coarse layout: WG-MAJOR -- coarse[(wg*NB + b)*CAPW + li]. Round-7 post-mortem:
// bucket-major spread each wave's 64 stores over ~60 segments strided 112KB
// across 22.9MB (every 8B store its own L2-missing transaction, multi-round-trip
// line fills). WG-major gives each wg a private 88KB window -> ~2.8MB L2 working
// set per XCD, lines fill in-cache and write back to HBM exactly once.
// final payload (u32): (col << 16) | bf16bits(val); cursor[r] = exact count.
//
// NT policy (round-4 post-mortem): xb/coarse/payload are producer->consumer
// buffers -- CACHED stores so they land in LLC at kernel end. NT only for:
// payload loads in gather (read-once) and out stores (write-once, never read).

// Pass A (fused with x->bf16 conversion -- round-7 post-mortem: splitting cost
// ~9us of lost overlap + launch gap): per-wg compaction into (bucket, wg)
// segments using LDS counters only (round-2 post-mortem: global atomics cost
// ~100MB HBM write traffic + serialize at HBM latency). Per-wg overflow region
// (count written unconditionally) -> no host-side memset dispatch needed.
__global__ void __launch_bounds__(A_THREADS) convA_kernel(const float* __restrict__ x,
                                                          uint32_t* __restrict__ xb,
                                                          const float* __restrict__ adj_vals,
                                                          const int* __restrict__ row,
                                                          const int* __restrict__ col,
                                                          uint64_t* __restrict__ coarse,
                                                          uint32_t* __restrict__ lens,
                                                          uint32_t* __restrict__ ovfcA,
                                                          uint64_t* __restrict__ ovfA) {
  __shared__ uint32_t cnt[NB];
  __shared__ uint32_t ovfc;
  int wg = blockIdx.x;
  int tid = threadIdx.x;
  if (tid < NB) cnt[tid] = 0;
  if (tid == 0) ovfc = 0;

  // phase 0: x -> bf16, 32B in / 16B out per iteration (cached stores -> LLC)
  const int gthreads = NWG_A * A_THREADS;
  for (int i = wg * A_THREADS + tid; i < (N_NODES * N_FEAT) / 8; i += gthreads) {
    f4v a = ((const f4v*)x)[2 * i];
    f4v b = ((const f4v*)x)[2 * i + 1];
    u4v o;
    o.x = f2bf(__float_as_uint(a.x)) | (f2bf(__float_as_uint(a.y)) << 16);
    o.y = f2bf(__float_as_uint(a.z)) | (f2bf(__float_as_uint(a.w)) << 16);
    o.z = f2bf(__float_as_uint(b.x)) | (f2bf(__float_as_uint(b.y)) << 16);
    o.w = f2bf(__float_as_uint(b.z)) | (f2bf(__float_as_uint(b.w)) << 16);
    ((u4v*)xb)[i] = o;
  }
  __syncthreads();  // cnt/ovfc init visible

  // phase 1: bin 4-edge chunks (vector loads), LDS-atomic slot ranks,
  // wg-major coarse scatter (private 88KB window -> L2-resident)
  uint64_t* my_coarse = coarse + (size_t)wg * NB * CAPW;
  for (int ch = tid; ch < CHUNKS_PW; ch += A_THREADS) {
    const int g = wg * CHUNKS_PW + ch;     // global chunk; edges [4g, 4g+4)
    const int4 r4 = ((const int4*)row)[g];
    const int4 c4 = ((const int4*)col)[g];
    const float4 a4 = ((const float4*)adj_vals)[g];
    const int rr[4] = {r4.x, r4.y, r4.z, r4.w};
    const int cc[4] = {c4.x, c4.y, c4.z, c4.w};
    const float aa[4] = {a4.x, a4.y, a4.z, a4.w};
#pragma unroll
    for (int k = 0; k < 4; ++k) {
      const uint32_t e = (uint32_t)(4 * g + k);
      if (!edge_keep(e)) continue;
      const uint32_t r = (uint32_t)rr[k];
      const uint32_t c = (uint32_t)cc[k];
      const float v = aa[k] / 0.9f;
      const uint32_t b = r >> RSHIFT;
      const uint32_t li = atomicAdd(&cnt[b], 1u);
      const uint64_t p = ((uint64_t)r << 48) | ((uint64_t)c << 32) | (uint64_t)__float_as_uint(v);
      if (li < CAPW) {
        my_coarse[(size_t)b * CAPW + li] = p;
      } else {
        const uint32_t oi = atomicAdd(&ovfc, 1u);
        if (oi < OVF_PW) ovfA[(size_t)wg * OVF_PW + oi] = p;
      }
    }
  }
  __syncthreads();
  if (tid < NB) lens[(size_t)tid * NWG_A + wg] = min(cnt[tid], (uint32_t)CAPW);
  if (tid == 0) ovfcA[wg] = min(ovfc, (uint32_t)OVF_PW);
}

// Pass B: one 1024-thread wg per 256-row bucket. Segment lengths prefetched to
// LDS. HALF-WAVE (32-lane) per segment (mean len 29.4: doubles active lanes,
// halves dependent-chain count vs full-wave). Reads wg-major coarse: 448B
// contiguous per segment, stride 88KB between segments (64B-line granular, no
// penalty). Rows padded with zero-words to a multiple of 8 so the gather needs
// no masking.
__global__ void __launch_bounds__(1024) partB_kernel(const uint64_t* __restrict__ coarse,
                                                     const uint32_t* __restrict__ lens,
                                                     uint32_t* __restrict__ payload,
                                                     uint32_t* __restrict__ cursor,
                                                     uint32_t* __restrict__ ovfcB,
                                                     uint64_t* __restrict__ ovfB) {
  int b = blockIdx.x;
  int tid = threadIdx.x;
  __shared__ uint32_t cnt[BROWS];   // per local-row fill count
  __shared__ uint32_t s_len[NWG_A];
  __shared__ uint32_t ovfc;
  if (tid < BROWS) cnt[tid] = 0;
  if (tid < NWG_A) s_len[tid] = lens[(size_t)b * NWG_A + tid];
  if (tid == 0) ovfc = 0;
  __syncthreads();

  int hw = tid >> 5;     // 32 half-waves
  int lane = tid & 31;
  for (int seg = hw; seg < NWG_A; seg += 32) {
    uint32_t len = s_len[seg];   // half-wave-uniform, LDS
    const uint64_t* cseg = coarse + ((size_t)seg * NB + b) * CAPW;
    for (uint32_t li = (uint32_t)lane; li < len; li += 32) {
      uint64_t p = cseg[li];
      uint32_t r = (uint32_t)(p >> 48);
      uint32_t rl = r & (BROWS - 1);
      uint32_t idx = atomicAdd(&cnt[rl], 1u);
      if (idx < CAP) {
        uint32_t c = (uint32_t)(p >> 32) & 0xFFFFu;
        payload[(size_t)r * CAP + idx] = (c << 16) | f2bf((uint32_t)p);
      } else {
        uint32_t oi = atomicAdd(&ovfc, 1u);
        if (oi < OVF_PB) ovfB[(size_t)b * OVF_PB + oi] = p;
      }
    }
  }
  __syncthreads();
  // exact count to cursor; zero-pad slots to a multiple of 8
  if (tid < BROWS) {
    uint32_t r = ((uint32_t)b << RSHIFT) + (uint32_t)tid;
    if (r < N_NODES) {
      uint32_t c0 = min(cnt[tid], (uint32_t)CAP);
      cursor[r] = c0;
      uint32_t np = min((c0 + 7u) & ~7u, (uint32_t)CAP);
      for (uint32_t i2 = c0; i2 < np; ++i2) payload[(size_t)r * CAP + i2] = 0u;
    }
  }
  if (tid == 0) ovfcB[b] = min(ovfc, (uint32_t)OVF_PB);
}

// Gather from bf16 x: 16-lane teams per row (dwordx4 = 8 feats/lane), 16 teams
// per 256-thread block. ROUND-1 PROVEN FORM (43us): padded slot count, no
// register masking, and ALL payload chunks preloaded BEFORE the compute chain
// (rounds 4/5 post-mortem: lazy mid-loop p2/p3 loads serialize an un-overlapped
// LLC round-trip for the ~35% of rows with >32 edges -- cost ~4us).
__global__ void __launch_bounds__(256) gather_bf16_kernel(const uint32_t* __restrict__ xb,
                                                          const uint32_t* __restrict__ payload,
                                                          const uint32_t* __restrict__ cursor,
                                                          float* __restrict__ out) {
  int r = blockIdx.x * 16 + (threadIdx.x >> 4);
  int lane = threadIdx.x & 15;
  uint32_t base = (uint32_t)r * CAP;
  uint32_t cnt = cursor[r];                   // exact count, <= CAP
  uint32_t n = (cnt + 7u) & ~7u;              // padded count; pads are zeros
  const uint4* x4 = (const uint4*)xb;         // row stride: 16 uint4 (128 bf16)

  float acc0 = 0.f, acc1 = 0.f, acc2 = 0.f, acc3 = 0.f;
  float acc4 = 0.f, acc5 = 0.f, acc6 = 0.f, acc7 = 0.f;

  // preload ALL payload chunks this row needs (coalesced 64B per team, NT)
  uint32_t p0 = __builtin_nontemporal_load(payload + base + lane);
  uint32_t p1 = __builtin_nontemporal_load(payload + base + 16 + lane);
  uint32_t p2 = (n > 32u) ? __builtin_nontemporal_load(payload + base + 32 + lane) : 0u;
  uint32_t p3 = (n > 48u) ? __builtin_nontemporal_load(payload + base + 48 + lane) : 0u;

#define GSTEP(ww)                                                            \
  {                                                                          \
    uint32_t cc = (ww) >> 16;                                                \
    float vv = __uint_as_float((ww) << 16);                                  \
    uint4 a = x4[(size_t)cc * 16 + lane];                                    \
    acc0 += vv * __uint_as_float(a.x << 16);                                 \
    acc1 += vv * __uint_as_float(a.x & 0xffff0000u);                         \
    acc2 += vv * __uint_as_float(a.y << 16);                                 \
    acc3 += vv * __uint_as_float(a.y & 0xffff0000u);                         \
    acc4 += vv * __uint_as_float(a.z << 16);                                 \
    acc5 += vv * __uint_as_float(a.z & 0xffff0000u);                         \
    acc6 += vv * __uint_as_float(a.w << 16);                                 \
    acc7 += vv * __uint_as_float(a.w & 0xffff0000u);                         \
  }

#define PCHUNK(preg, mm)                                                     \
  for (int j = 0; j < (mm); j += 8) {                                        \
    uint32_t w0 = __shfl((preg), j + 0, 16);                                 \
    uint32_t w1 = __shfl((preg), j + 1, 16);                                 \
    uint32_t w2 = __shfl((preg), j + 2, 16);                                 \
    uint32_t w3 = __shfl((preg), j + 3, 16);                                 \
    uint32_t w4 = __shfl((preg), j + 4, 16);                                 \
    uint32_t w5 = __shfl((preg), j + 5, 16);                                 \
    uint32_t w6 = __shfl((preg), j + 6, 16);                                 \
    uint32_t w7 = __shfl((preg), j + 7, 16);                                 \
    GSTEP(w0) GSTEP(w1) GSTEP(w2) GSTEP(w3)                                  \
    GSTEP(w4) GSTEP(w5) GSTEP(w6) GSTEP(w7)                                  \
  }

  int rem = (int)n;   // multiple of 8
  PCHUNK(p0, min(rem, 16));
  rem -= 16;
  if (rem > 0) {
    PCHUNK(p1, min(rem, 16));
    rem -= 16;
    if (rem > 0) {
      PCHUNK(p2, min(rem, 16));
      rem -= 16;
      if (rem > 0) {
        PCHUNK(p3, min(rem, 16));
      }
    }
  }
#undef PCHUNK
#undef GSTEP

  // lane stores feats 8*lane .. 8*lane+7 -> 512B contiguous per team (NT)
  f4v lo, hi;
  lo.x = acc0; lo.y = acc1; lo.z = acc2; lo.w = acc3;
  hi.x = acc4; hi.y = acc5; hi.z = acc6; hi.w = acc7;
  f4v* o = (f4v*)out + (size_t)r * 32 + lane * 2;
  __builtin_nontemporal_store(lo, o);
  __builtin_nontemporal_store(hi, o + 1);
}

// exact cleanup for packed (row,col,f32val) overflow entries. Early-exits when
// all 446 region counts are zero (the expected case).
__global__ void __launch_bounds__(256) ovf_pack_kernel(const float* __restrict__ x,
                                                       const uint32_t* __restrict__ ovfcA,
                                                       const uint64_t* __restrict__ ovfA,
                                                       const uint32_t* __restrict__ ovfcB,
                                                       const uint64_t* __restrict__ ovfB,
                                                       float* __restrict__ out) {
  __shared__ int any;
  if (threadIdx.x == 0) any = 0;
  __syncthreads();
  for (int t = threadIdx.x; t < NREG; t += 256) {
    uint32_t c = (t < NWG_A) ? ovfcA[t] : ovfcB[t - NWG_A];
    if (c) any = 1;
  }
  __syncthreads();
  if (!any) return;

  int group = (int)((blockIdx.x * 256 + threadIdx.x) >> 7);
  int f = threadIdx.x & 127;
  const int ngroups = (16 * 256) >> 7;  // 32 groups
  for (int reg = group; reg < NREG; reg += ngroups) {
    uint32_t c;
    const uint64_t* basep;
    if (reg < NWG_A) {
      c = min(ovfcA[reg], (uint32_t)OVF_PW);
      basep = ovfA + (size_t)reg * OVF_PW;
    } else {
      c = min(ovfcB[reg - NWG_A], (uint32_t)OVF_PB);
      basep = ovfB + (size_t)(reg - NWG_A) * OVF_PB;
    }
    for (uint32_t i = 0; i < c; ++i) {
      uint64_t p = basep[i];
      uint32_t r = (uint32_t)(p >> 48);
      uint32_t cc = (uint32_t)((p >> 32) & 0xFFFFu);
      float v = __uint_as_float((uint32_t)p);
      atomicAdd(&out[(size_t)r * N_FEAT + f], v * x[(size_t)cc * N_FEAT + f]);
    }
  }
}

// =================== FALLBACK: fused atomic scatter ============================

__global__ void __launch_bounds__(256) scatter_fused_kernel(const float* __restrict__ x,
                                                            const float* __restrict__ adj_vals,
                                                            const int* __restrict__ row,
                                                            const int* __restrict__ col,
                                                            float* __restrict__ out) {
  long long t = (long long)blockIdx.x * blockDim.x + threadIdx.x;
  int e = (int)(t >> 6);
  int lane = (int)(t & 63);
  if (e >= N_EDGES) return;
  if (!edge_keep((uint32_t)e)) return;
  float v = adj_vals[e] / 0.9f;
  float2 xf = *(const float2*)(x + (long long)col[e] * N_FEAT + lane * 2);
  float* dst = out + (long long)row[e] * N_FEAT + lane * 2;
  atomicAdd(dst, v * xf.x);
  atomicAdd(dst + 1, v * xf.y);
}

// ---------------- launch --------------------------------------------------------

extern "C" void kernel_launch(void* const* d_in, const int* in_sizes, int n_in,
                              void* d_out, int out_size, void* d_ws, size_t ws_size,
                              hipStream_t stream) {
  const float* x        = (const float*)d_in[0];
  const float* adj_vals = (const float*)d_in[1];
  const int*   row      = (const int*)d_in[2];
  const int*   col      = (const int*)d_in[3];
  float* out = (float*)d_out;

  // ---- workspace layout (nothing needs host-side init) ----
  size_t a_cursor  = 0;                                                    // N u32
  size_t a_ovfcA   = (a_cursor + (size_t)N_NODES * 4 + 255) & ~255ull;     // NWG_A u32
  size_t a_ovfcB   = (a_ovfcA + (size_t)NWG_A * 4 + 255) & ~255ull;        // NB u32
  size_t a_lens    = (a_ovfcB + (size_t)NB * 4 + 255) & ~255ull;           // NB*NWG_A u32
  size_t a_ovfA    = (a_lens + (size_t)NB * NWG_A * 4 + 255) & ~255ull;    // NWG_A*OVF_PW u64
  size_t a_ovfB    = (a_ovfA + (size_t)NWG_A * OVF_PW * 8 + 255) & ~255ull; // NB*OVF_PB u64
  size_t a_coarse  = (a_ovfB + (size_t)NB * OVF_PB * 8 + 255) & ~255ull;   // NWG_A*NB*CAPW u64
  size_t a_payload = (a_coarse + (size_t)NWG_A * NB * CAPW * 8 + 255) & ~255ull;  // N*CAP u32
  size_t a_xb      = (a_payload + (size_t)N_NODES * CAP * 4 + 255) & ~255ull;     // N*F bf16
  size_t need      = a_xb + (size_t)N_NODES * N_FEAT * 2;

  if (ws_size >= need) {
    uint32_t* cursor  = (uint32_t*)((char*)d_ws + a_cursor);
    uint32_t* ovfcA   = (uint32_t*)((char*)d_ws + a_ovfcA);
    uint32_t* ovfcB   = (uint32_t*)((char*)d_ws + a_ovfcB);
    uint32_t* lens    = (uint32_t*)((char*)d_ws + a_lens);
    uint64_t* ovfA    = (uint64_t*)((char*)d_ws + a_ovfA);
    uint64_t* ovfB    = (uint64_t*)((char*)d_ws + a_ovfB);
    uint64_t* coarse  = (uint64_t*)((char*)d_ws + a_coarse);
    uint32_t* payload = (uint32_t*)((char*)d_ws + a_payload);
    uint32_t* xb      = (uint32_t*)((char*)d_ws + a_xb);

    convA_kernel<<<NWG_A, A_THREADS, 0, stream>>>(x, xb, adj_vals, row, col,
                                                  coarse, lens, ovfcA, ovfA);
    partB_kernel<<<NB, 1024, 0, stream>>>(coarse, lens, payload, cursor, ovfcB, ovfB);
    gather_bf16_kernel<<<N_NODES / 16, 256, 0, stream>>>(xb, payload, cursor, out);
    ovf_pack_kernel<<<16, 256, 0, stream>>>(x, ovfcA, ovfA, ovfcB, ovfB, out);
  } else {
    hipMemsetAsync(d_out, 0, (size_t)out_size * sizeof(float), stream);
    long long total_threads = (long long)N_EDGES * 64;
    scatter_fused_kernel<<<(int)((total_threads + 255) / 256), 256, 0, stream>>>(
        x, adj_vals, row, col, out);
  }
}

// Round 9
// 155.054 us; speedup vs baseline: 1.1100x; 1.0539x over previous
//
#include <hip/hip_runtime.h>
#include <stdint.h>

#define N_NODES 50000
#define N_EDGES 1600000
#define N_FEAT 128
#define CAP 64            // final slots per row; Poisson(28.8) mean, +6.5 sigma
#define OVF_PW 256        // per-convA-wg overflow slots (expected usage: ~0)
#define OVF_PB 192        // per-bucket overflow slots (expected usage: ~0)

// radix-partition parameters
#define RSHIFT 7          // 128 rows per bucket (was 256): NB=391 blocks fills all CUs
#define BROWS 128
#define NB 391            // ceil(50000 / 128)
#define NWG_A 250         // pass-A workgroups; 250*1600 chunks * 4 edges = 1.6M exact
#define A_THREADS 1024
#define CHUNKS_PW 1600    // 4-edge chunks per pass-A wg
#define CAPW 40           // slots per (bucket, wg) segment; mean 14.7, +6.6 sigma
#define NREG (NWG_A + NB) // 641 overflow regions total

// ---------------- threefry2x32 (bit-exact, KAT-verified vs Random123) ----------

struct KeyPair { uint32_t a, b; };

__host__ __device__ constexpr inline uint32_t rotl32(uint32_t x, int r) {
  return (x << r) | (x >> (32 - r));
}

__host__ __device__ constexpr inline KeyPair threefry2x32(uint32_t k0, uint32_t k1,
                                                          uint32_t x0, uint32_t x1) {
  const uint32_t ks0 = k0, ks1 = k1, ks2 = k0 ^ k1 ^ 0x1BD11BDAu;
  x0 += ks0;
  x1 += ks1;
  const int rotA[4] = {13, 15, 26, 6};
  const int rotB[4] = {17, 29, 16, 24};
  const uint32_t ks[3] = {ks0, ks1, ks2};
  for (int i = 0; i < 5; ++i) {
    const int* rot = (i & 1) ? rotB : rotA;
    for (int j = 0; j < 4; ++j) {
      x0 += x1;
      x1 = rotl32(x1, rot[j]);
      x1 ^= x0;
    }
    x0 += ks[(i + 1) % 3];
    x1 += ks[(i + 2) % 3] + (uint32_t)(i + 1);
  }
  return {x0, x1};
}

// mask_key = fold_in(key(42), 7); compile-time.
constexpr KeyPair MASK_KEY = threefry2x32(0u, 42u, 0u, 7u);

// Partitionable (counter-mode) random_bits: element i -> threefry(key, (0, i)), bits = b1^b2.
__device__ inline bool edge_keep(uint32_t e) {
  KeyPair r = threefry2x32(MASK_KEY.a, MASK_KEY.b, 0u, e);
  uint32_t bits = r.a ^ r.b;
  float u = __uint_as_float((bits >> 9) | 0x3f800000u) - 1.0f;
  return u < 0.9f;
}

// fp32 bits -> bf16 with round-to-nearest-even
__device__ inline uint32_t f2bf(uint32_t b) {
  return (b + 0x7fffu + ((b >> 16) & 1u)) >> 16;
}

// true vector types (ext_vector_type) -- __builtin_nontemporal_* rejects HIP's
// class-type uint2/float4, but accepts these (identical layout & codegen).
typedef uint32_t u4v __attribute__((ext_vector_type(4)));
typedef float f4v __attribute__((ext_vector_type(4)));

// =================== PRIMARY PATH ==============================================
// coarse pack: (row << 48) | (col << 32) | f32bits(val), wg-major layout
// (coarse[(wg*NB + b)*CAPW + li], round-8: private per-wg window).
// Rounds 4-8 post-mortems baked in: no global atomics (r2), cached
// producer->consumer stores / NT only for read-once+write-once (r4), eager
// preloads (r5), fused conversion (r7). Round 9: payload lives in LDS inside a
// merged rank+gather kernel -- the 26MB payload round-trip, pad pass, cursor
// buffer, one dispatch, and the gather shfl machinery are all deleted.

// Pass A (fused with x->bf16 conversion): per-wg compaction into (bucket, wg)
// segments using LDS counters only. Per-wg overflow region (count written
// unconditionally) -> no host-side memset dispatch needed.
__global__ void __launch_bounds__(A_THREADS) convA_kernel(const float* __restrict__ x,
                                                          uint32_t* __restrict__ xb,
                                                          const float* __restrict__ adj_vals,
                                                          const int* __restrict__ row,
                                                          const int* __restrict__ col,
                                                          uint64_t* __restrict__ coarse,
                                                          uint32_t* __restrict__ lens,
                                                          uint32_t* __restrict__ ovfcA,
                                                          uint64_t* __restrict__ ovfA) {
  __shared__ uint32_t cnt[NB];
  __shared__ uint32_t ovfc;
  int wg = blockIdx.x;
  int tid = threadIdx.x;
  if (tid < NB) cnt[tid] = 0;
  if (tid == 0) ovfc = 0;

  // phase 0: x -> bf16, 32B in / 16B out per iteration (cached stores -> LLC)
  const int gthreads = NWG_A * A_THREADS;
  for (int i = wg * A_THREADS + tid; i < (N_NODES * N_FEAT) / 8; i += gthreads) {
    f4v a = ((const f4v*)x)[2 * i];
    f4v b = ((const f4v*)x)[2 * i + 1];
    u4v o;
    o.x = f2bf(__float_as_uint(a.x)) | (f2bf(__float_as_uint(a.y)) << 16);
    o.y = f2bf(__float_as_uint(a.z)) | (f2bf(__float_as_uint(a.w)) << 16);
    o.z = f2bf(__float_as_uint(b.x)) | (f2bf(__float_as_uint(b.y)) << 16);
    o.w = f2bf(__float_as_uint(b.z)) | (f2bf(__float_as_uint(b.w)) << 16);
    ((u4v*)xb)[i] = o;
  }
  __syncthreads();  // cnt/ovfc init visible

  // phase 1: bin 4-edge chunks (vector loads), LDS-atomic slot ranks,
  // wg-major coarse scatter (private ~125KB window -> L2-resident)
  uint64_t* my_coarse = coarse + (size_t)wg * NB * CAPW;
  for (int ch = tid; ch < CHUNKS_PW; ch += A_THREADS) {
    const int g = wg * CHUNKS_PW + ch;     // global chunk; edges [4g, 4g+4)
    const int4 r4 = ((const int4*)row)[g];
    const int4 c4 = ((const int4*)col)[g];
    const float4 a4 = ((const float4*)adj_vals)[g];
    const int rr[4] = {r4.x, r4.y, r4.z, r4.w};
    const int cc[4] = {c4.x, c4.y, c4.z, c4.w};
    const float aa[4] = {a4.x, a4.y, a4.z, a4.w};
#pragma unroll
    for (int k = 0; k < 4; ++k) {
      const uint32_t e = (uint32_t)(4 * g + k);
      if (!edge_keep(e)) continue;
      const uint32_t r = (uint32_t)rr[k];
      const uint32_t c = (uint32_t)cc[k];
      const float v = aa[k] / 0.9f;
      const uint32_t b = r >> RSHIFT;
      const uint32_t li = atomicAdd(&cnt[b], 1u);
      const uint64_t p = ((uint64_t)r << 48) | ((uint64_t)c << 32) | (uint64_t)__float_as_uint(v);
      if (li < CAPW) {
        my_coarse[(size_t)b * CAPW + li] = p;
      } else {
        const uint32_t oi = atomicAdd(&ovfc, 1u);
        if (oi < OVF_PW) ovfA[(size_t)wg * OVF_PW + oi] = p;
      }
    }
  }
  __syncthreads();
  if (tid < NB) lens[(size_t)tid * NWG_A + wg] = min(cnt[tid], (uint32_t)CAPW);
  if (tid == 0) ovfcA[wg] = min(ovfc, (uint32_t)OVF_PW);
}

// Merged rank + gather: one 512-thread wg per 128-row bucket (391 wgs -> all
// 256 CUs busy; ~34KB LDS -> multiple wgs/CU co-resident so the rank phase's
// latency hides under other wgs' fabric-bound gather loads).
//   rank:   16-lane teams read (seg,b) coarse segments (NT, read-once),
//           LDS-atomic rank into cnt[], scatter payload word into LDS tile.
//   gather: 16-lane teams, 4 rows each; payload slots read as wave-uniform LDS
//           broadcasts (no shuffles); LDS tile pre-zeroed so padded tail words
//           contribute exactly 0; x4 loads cached (xb reuse via L2/LLC).
__global__ void __launch_bounds__(512) rank_gather_kernel(const uint32_t* __restrict__ xb,
                                                          const uint64_t* __restrict__ coarse,
                                                          const uint32_t* __restrict__ lens,
                                                          uint32_t* __restrict__ ovfcB,
                                                          uint64_t* __restrict__ ovfB,
                                                          float* __restrict__ out) {
  int b = blockIdx.x;
  int tid = threadIdx.x;
  __shared__ uint32_t pay[BROWS * CAP];   // 32 KB payload tile
  __shared__ uint32_t cnt[BROWS];
  __shared__ uint32_t s_len[NWG_A];
  __shared__ uint32_t ovfc;
  for (int i = tid; i < BROWS * CAP; i += 512) pay[i] = 0u;
  if (tid < BROWS) cnt[tid] = 0;
  if (tid < NWG_A) s_len[tid] = lens[(size_t)b * NWG_A + tid];
  if (tid == 0) ovfc = 0;
  __syncthreads();

  int team = tid >> 4;        // 32 teams of 16 lanes
  int lane = tid & 15;

  // ---- rank phase ----
  for (int seg = team; seg < NWG_A; seg += 32) {
    uint32_t len = s_len[seg];   // team-uniform
    const uint64_t* cseg = coarse + ((size_t)seg * NB + b) * CAPW;
    for (uint32_t li = (uint32_t)lane; li < len; li += 16) {
      uint64_t p = __builtin_nontemporal_load(cseg + li);
      uint32_t r = (uint32_t)(p >> 48);
      uint32_t rl = r & (BROWS - 1);
      uint32_t idx = atomicAdd(&cnt[rl], 1u);
      if (idx < CAP) {
        uint32_t c = (uint32_t)(p >> 32) & 0xFFFFu;
        pay[rl * CAP + idx] = (c << 16) | f2bf((uint32_t)p);
      } else {
        uint32_t oi = atomicAdd(&ovfc, 1u);
        if (oi < OVF_PB) ovfB[(size_t)b * OVF_PB + oi] = p;
      }
    }
  }
  __syncthreads();
  if (tid == 0) ovfcB[b] = min(ovfc, (uint32_t)OVF_PB);

  // ---- gather phase ----
  const uint4* x4 = (const uint4*)xb;     // row stride: 16 uint4 (128 bf16)
  const int r0 = b << RSHIFT;

#define GSTEP(ww)                                                            \
  {                                                                          \
    uint32_t cc = (ww) >> 16;                                                \
    float vv = __uint_as_float((ww) << 16);                                  \
    uint4 a = x4[(size_t)cc * 16 + lane];                                    \
    acc0 += vv * __uint_as_float(a.x << 16);                                 \
    acc1 += vv * __uint_as_float(a.x & 0xffff0000u);                         \
    acc2 += vv * __uint_as_float(a.y << 16);                                 \
    acc3 += vv * __uint_as_float(a.y & 0xffff0000u);                         \
    acc4 += vv * __uint_as_float(a.z << 16);                                 \
    acc5 += vv * __uint_as_float(a.z & 0xffff0000u);                         \
    acc6 += vv * __uint_as_float(a.w << 16);                                 \
    acc7 += vv * __uint_as_float(a.w & 0xffff0000u);                         \
  }

  for (int rl = team; rl < BROWS; rl += 32) {
    int r = r0 + rl;
    if (r >= N_NODES) continue;
    uint32_t n = (min(cnt[rl], (uint32_t)CAP) + 7u) & ~7u;  // pads are zeros
    const uint32_t* prow = &pay[rl * CAP];
    float acc0 = 0.f, acc1 = 0.f, acc2 = 0.f, acc3 = 0.f;
    float acc4 = 0.f, acc5 = 0.f, acc6 = 0.f, acc7 = 0.f;
    for (uint32_t j = 0; j < n; j += 8) {
      // 8 wave-uniform LDS broadcast reads, then 8 x-row loads in flight
      uint32_t w0 = prow[j + 0];
      uint32_t w1 = prow[j + 1];
      uint32_t w2 = prow[j + 2];
      uint32_t w3 = prow[j + 3];
      uint32_t w4 = prow[j + 4];
      uint32_t w5 = prow[j + 5];
      uint32_t w6 = prow[j + 6];
      uint32_t w7 = prow[j + 7];
      GSTEP(w0) GSTEP(w1) GSTEP(w2) GSTEP(w3)
      GSTEP(w4) GSTEP(w5) GSTEP(w6) GSTEP(w7)
    }
    f4v lo, hi;
    lo.x = acc0; lo.y = acc1; lo.z = acc2; lo.w = acc3;
    hi.x = acc4; hi.y = acc5; hi.z = acc6; hi.w = acc7;
    f4v* o = (f4v*)out + (size_t)r * 32 + lane * 2;
    __builtin_nontemporal_store(lo, o);
    __builtin_nontemporal_store(hi, o + 1);
  }
#undef GSTEP
}

// exact cleanup for packed (row,col,f32val) overflow entries. Early-exits when
// all 641 region counts are zero (the expected case).
__global__ void __launch_bounds__(256) ovf_pack_kernel(const float* __restrict__ x,
                                                       const uint32_t* __restrict__ ovfcA,
                                                       const uint64_t* __restrict__ ovfA,
                                                       const uint32_t* __restrict__ ovfcB,
                                                       const uint64_t* __restrict__ ovfB,
                                                       float* __restrict__ out) {
  __shared__ int any;
  if (threadIdx.x == 0) any = 0;
  __syncthreads();
  for (int t = threadIdx.x; t < NREG; t += 256) {
    uint32_t c = (t < NWG_A) ? ovfcA[t] : ovfcB[t - NWG_A];
    if (c) any = 1;
  }
  __syncthreads();
  if (!any) return;

  int group = (int)((blockIdx.x * 256 + threadIdx.x) >> 7);
  int f = threadIdx.x & 127;
  const int ngroups = (16 * 256) >> 7;  // 32 groups
  for (int reg = group; reg < NREG; reg += ngroups) {
    uint32_t c;
    const uint64_t* basep;
    if (reg < NWG_A) {
      c = min(ovfcA[reg], (uint32_t)OVF_PW);
      basep = ovfA + (size_t)reg * OVF_PW;
    } else {
      c = min(ovfcB[reg - NWG_A], (uint32_t)OVF_PB);
      basep = ovfB + (size_t)(reg - NWG_A) * OVF_PB;
    }
    for (uint32_t i = 0; i < c; ++i) {
      uint64_t p = basep[i];
      uint32_t r = (uint32_t)(p >> 48);
      uint32_t cc = (uint32_t)((p >> 32) & 0xFFFFu);
      float v = __uint_as_float((uint32_t)p);
      atomicAdd(&out[(size_t)r * N_FEAT + f], v * x[(size_t)cc * N_FEAT + f]);
    }
  }
}

// =================== FALLBACK: fused atomic scatter ============================

__global__ void __launch_bounds__(256) scatter_fused_kernel(const float* __restrict__ x,
                                                            const float* __restrict__ adj_vals,
                                                            const int* __restrict__ row,
                                                            const int* __restrict__ col,
                                                            float* __restrict__ out) {
  long long t = (long long)blockIdx.x * blockDim.x + threadIdx.x;
  int e = (int)(t >> 6);
  int lane = (int)(t & 63);
  if (e >= N_EDGES) return;
  if (!edge_keep((uint32_t)e)) return;
  float v = adj_vals[e] / 0.9f;
  float2 xf = *(const float2*)(x + (long long)col[e] * N_FEAT + lane * 2);
  float* dst = out + (long long)row[e] * N_FEAT + lane * 2;
  atomicAdd(dst, v * xf.x);
  atomicAdd(dst + 1, v * xf.y);
}

// ---------------- launch --------------------------------------------------------

extern "C" void kernel_launch(void* const* d_in, const int* in_sizes, int n_in,
                              void* d_out, int out_size, void* d_ws, size_t ws_size,
                              hipStream_t stream) {
  const float* x        = (const float*)d_in[0];
  const float* adj_vals = (const float*)d_in[1];
  const int*   row      = (const int*)d_in[2];
  const int*   col      = (const int*)d_in[3];
  float* out = (float*)d_out;

  // ---- workspace layout (nothing needs host-side init) ----
  size_t a_ovfcA   = 0;                                                    // NWG_A u32
  size_t a_ovfcB   = (a_ovfcA + (size_t)NWG_A * 4 + 255) & ~255ull;        // NB u32
  size_t a_lens    = (a_ovfcB + (size_t)NB * 4 + 255) & ~255ull;           // NB*NWG_A u32
  size_t a_ovfA    = (a_lens + (size_t)NB * NWG_A * 4 + 255) & ~255ull;    // NWG_A*OVF_PW u64
  size_t a_ovfB    = (a_ovfA + (size_t)NWG_A * OVF_PW * 8 + 255) & ~255ull; // NB*OVF_PB u64
  size_t a_coarse  = (a_ovfB + (size_t)NB * OVF_PB * 8 + 255) & ~255ull;   // NWG_A*NB*CAPW u64
  size_t a_xb      = (a_coarse + (size_t)NWG_A * NB * CAPW * 8 + 255) & ~255ull;  // N*F bf16
  size_t need      = a_xb + (size_t)N_NODES * N_FEAT * 2;

  if (ws_size >= need) {
    uint32_t* ovfcA   = (uint32_t*)((char*)d_ws + a_ovfcA);
    uint32_t* ovfcB   = (uint32_t*)((char*)d_ws + a_ovfcB);
    uint32_t* lens    = (uint32_t*)((char*)d_ws + a_lens);
    uint64_t* ovfA    = (uint64_t*)((char*)d_ws + a_ovfA);
    uint64_t* ovfB    = (uint64_t*)((char*)d_ws + a_ovfB);
    uint64_t* coarse  = (uint64_t*)((char*)d_ws + a_coarse);
    uint32_t* xb      = (uint32_t*)((char*)d_ws + a_xb);

    convA_kernel<<<NWG_A, A_THREADS, 0, stream>>>(x, xb, adj_vals, row, col,
                                                  coarse, lens, ovfcA, ovfA);
    rank_gather_kernel<<<NB, 512, 0, stream>>>(xb, coarse, lens, ovfcB, ovfB, out);
    ovf_pack_kernel<<<16, 256, 0, stream>>>(x, ovfcA, ovfA, ovfcB, ovfB, out);
  } else {
    hipMemsetAsync(d_out, 0, (size_t)out_size * sizeof(float), stream);
    long long total_threads = (long long)N_EDGES * 64;
    scatter_fused_kernel<<<(int)((total_threads + 255) / 256), 256, 0, stream>>>(
        x, adj_vals, row, col, out);
  }
}

// Round 10
// 152.081 us; speedup vs baseline: 1.1317x; 1.0196x over previous
//
#include <hip/hip_runtime.h>
#include <stdint.h>

#define N_NODES 50000
#define N_EDGES 1600000
#define N_FEAT 128
#define CAP 64            // final slots per row; Poisson(28.8) mean, +6.5 sigma
#define OVF_PW 256        // per-convA-wg overflow slots (expected usage: ~0)
#define OVF_PB 192        // per-bucket overflow slots (expected usage: ~0)

// radix-partition parameters
#define RSHIFT 7          // 128 rows per bucket: NB=391 blocks fills all CUs
#define BROWS 128
#define NB 391            // ceil(50000 / 128)
#define NWG_A 250         // pass-A workgroups; 250*1600 chunks * 4 edges = 1.6M exact
#define A_THREADS 1024
#define CHUNKS_PW 1600    // 4-edge chunks per pass-A wg
#define CAPW 40           // slots per (bucket, wg) segment; mean 14.7, +6.6 sigma
#define NREG (NWG_A + NB) // 641 overflow regions total

// ---------------- threefry2x32 (bit-exact, KAT-verified vs Random123) ----------

struct KeyPair { uint32_t a, b; };

__host__ __device__ constexpr inline uint32_t rotl32(uint32_t x, int r) {
  return (x << r) | (x >> (32 - r));
}

__host__ __device__ constexpr inline KeyPair threefry2x32(uint32_t k0, uint32_t k1,
                                                          uint32_t x0, uint32_t x1) {
  const uint32_t ks0 = k0, ks1 = k1, ks2 = k0 ^ k1 ^ 0x1BD11BDAu;
  x0 += ks0;
  x1 += ks1;
  const int rotA[4] = {13, 15, 26, 6};
  const int rotB[4] = {17, 29, 16, 24};
  const uint32_t ks[3] = {ks0, ks1, ks2};
  for (int i = 0; i < 5; ++i) {
    const int* rot = (i & 1) ? rotB : rotA;
    for (int j = 0; j < 4; ++j) {
      x0 += x1;
      x1 = rotl32(x1, rot[j]);
      x1 ^= x0;
    }
    x0 += ks[(i + 1) % 3];
    x1 += ks[(i + 2) % 3] + (uint32_t)(i + 1);
  }
  return {x0, x1};
}

// mask_key = fold_in(key(42), 7); compile-time.
constexpr KeyPair MASK_KEY = threefry2x32(0u, 42u, 0u, 7u);

// Partitionable (counter-mode) random_bits: element i -> threefry(key, (0, i)), bits = b1^b2.
__device__ inline bool edge_keep(uint32_t e) {
  KeyPair r = threefry2x32(MASK_KEY.a, MASK_KEY.b, 0u, e);
  uint32_t bits = r.a ^ r.b;
  float u = __uint_as_float((bits >> 9) | 0x3f800000u) - 1.0f;
  return u < 0.9f;
}

// fp32 bits -> bf16 with round-to-nearest-even
__device__ inline uint32_t f2bf(uint32_t b) {
  return (b + 0x7fffu + ((b >> 16) & 1u)) >> 16;
}

// true vector types (ext_vector_type) -- __builtin_nontemporal_* rejects HIP's
// class-type uint2/float4, but accepts these (identical layout & codegen).
typedef uint32_t u4v __attribute__((ext_vector_type(4)));
typedef int32_t  i4v __attribute__((ext_vector_type(4)));
typedef float    f4v __attribute__((ext_vector_type(4)));

// =================== PRIMARY PATH ==============================================
// coarse pack: (row << 48) | (col << 32) | f32bits(val), wg-major layout
// (coarse[(wg*NB + b)*CAPW + li], round-8: private per-wg window).
// Post-mortems baked in: no global atomics (r2), cached producer->consumer
// stores / NT for read-once streams (r4), eager preloads (r5), fused conversion
// (r7), LDS payload in merged rank+gather (r9, -8us). Round 10: rank phase
// preloads collapse the dependent segment-walk into 2 pipelined load rounds.

// Pass A (fused with x->bf16 conversion): per-wg compaction into (bucket, wg)
// segments using LDS counters only. Edge arrays + x are read-once -> NT loads
// (keep L2 for the wg-private coarse window and xb lines). Per-wg overflow
// region (count written unconditionally) -> no host-side memset needed.
__global__ void __launch_bounds__(A_THREADS) convA_kernel(const float* __restrict__ x,
                                                          uint32_t* __restrict__ xb,
                                                          const float* __restrict__ adj_vals,
                                                          const int* __restrict__ row,
                                                          const int* __restrict__ col,
                                                          uint64_t* __restrict__ coarse,
                                                          uint32_t* __restrict__ lens,
                                                          uint32_t* __restrict__ ovfcA,
                                                          uint64_t* __restrict__ ovfA) {
  __shared__ uint32_t cnt[NB];
  __shared__ uint32_t ovfc;
  int wg = blockIdx.x;
  int tid = threadIdx.x;
  if (tid < NB) cnt[tid] = 0;
  if (tid == 0) ovfc = 0;

  // phase 0: x -> bf16, 32B in / 16B out per iteration (NT in, cached out)
  const int gthreads = NWG_A * A_THREADS;
  for (int i = wg * A_THREADS + tid; i < (N_NODES * N_FEAT) / 8; i += gthreads) {
    f4v a = __builtin_nontemporal_load((const f4v*)x + 2 * i);
    f4v b = __builtin_nontemporal_load((const f4v*)x + 2 * i + 1);
    u4v o;
    o.x = f2bf(__float_as_uint(a.x)) | (f2bf(__float_as_uint(a.y)) << 16);
    o.y = f2bf(__float_as_uint(a.z)) | (f2bf(__float_as_uint(a.w)) << 16);
    o.z = f2bf(__float_as_uint(b.x)) | (f2bf(__float_as_uint(b.y)) << 16);
    o.w = f2bf(__float_as_uint(b.z)) | (f2bf(__float_as_uint(b.w)) << 16);
    ((u4v*)xb)[i] = o;
  }
  __syncthreads();  // cnt/ovfc init visible

  // phase 1: bin 4-edge chunks (NT vector loads), LDS-atomic slot ranks,
  // wg-major coarse scatter (private ~125KB window -> L2-resident)
  uint64_t* my_coarse = coarse + (size_t)wg * NB * CAPW;
  for (int ch = tid; ch < CHUNKS_PW; ch += A_THREADS) {
    const int g = wg * CHUNKS_PW + ch;     // global chunk; edges [4g, 4g+4)
    const i4v r4 = __builtin_nontemporal_load((const i4v*)row + g);
    const i4v c4 = __builtin_nontemporal_load((const i4v*)col + g);
    const f4v a4 = __builtin_nontemporal_load((const f4v*)adj_vals + g);
    const int rr[4] = {r4.x, r4.y, r4.z, r4.w};
    const int cc[4] = {c4.x, c4.y, c4.z, c4.w};
    const float aa[4] = {a4.x, a4.y, a4.z, a4.w};
#pragma unroll
    for (int k = 0; k < 4; ++k) {
      const uint32_t e = (uint32_t)(4 * g + k);
      if (!edge_keep(e)) continue;
      const uint32_t r = (uint32_t)rr[k];
      const uint32_t c = (uint32_t)cc[k];
      const float v = aa[k] / 0.9f;
      const uint32_t b = r >> RSHIFT;
      const uint32_t li = atomicAdd(&cnt[b], 1u);
      const uint64_t p = ((uint64_t)r << 48) | ((uint64_t)c << 32) | (uint64_t)__float_as_uint(v);
      if (li < CAPW) {
        my_coarse[(size_t)b * CAPW + li] = p;
      } else {
        const uint32_t oi = atomicAdd(&ovfc, 1u);
        if (oi < OVF_PW) ovfA[(size_t)wg * OVF_PW + oi] = p;
      }
    }
  }
  __syncthreads();
  if (tid < NB) lens[(size_t)tid * NWG_A + wg] = min(cnt[tid], (uint32_t)CAPW);
  if (tid == 0) ovfcA[wg] = min(ovfc, (uint32_t)OVF_PW);
}

// Merged rank + gather: one 512-thread wg per 128-row bucket.
// Round-10 rank restructure: the r9 form walked ~8 segments per team with a
// DEPENDENT chain (len -> NT load -> atomic -> scatter) x8 sequentially =
// ~12us latency-bound prologue (55.7us total vs 43us standalone gather at the
// same bytes). Now: unconditionally preload slot `lane` of all 8 segments
// (8 independent NT loads in flight; unwritten slots < CAPW are safe, masked
// by len), issue the 16..31 tail round, THEN process. ~2 serialized load
// rounds instead of ~10. len>32 is +4.5 sigma -> rare inline loop.
__global__ void __launch_bounds__(512) rank_gather_kernel(const uint32_t* __restrict__ xb,
                                                          const uint64_t* __restrict__ coarse,
                                                          const uint32_t* __restrict__ lens,
                                                          uint32_t* __restrict__ ovfcB,
                                                          uint64_t* __restrict__ ovfB,
                                                          float* __restrict__ out) {
  int b = blockIdx.x;
  int tid = threadIdx.x;
  __shared__ uint32_t pay[BROWS * CAP];   // 32 KB payload tile
  __shared__ uint32_t cnt[BROWS];
  __shared__ uint32_t s_len[NWG_A];
  __shared__ uint32_t ovfc;
  for (int i = tid; i < BROWS * CAP; i += 512) pay[i] = 0u;
  if (tid < BROWS) cnt[tid] = 0;
  if (tid < NWG_A) s_len[tid] = lens[(size_t)b * NWG_A + tid];
  if (tid == 0) ovfc = 0;
  __syncthreads();

  int team = tid >> 4;        // 32 teams of 16 lanes
  int lane = tid & 15;

  // ---- rank phase: preload rounds, then process ----
  uint32_t lenv[8];
  uint64_t pre[8];
#pragma unroll
  for (int s8 = 0; s8 < 8; ++s8) {
    int seg = team + (s8 << 5);
    lenv[s8] = (seg < NWG_A) ? s_len[seg] : 0u;
    // unconditional first-16 preload (slot `lane` always < CAPW allocation)
    pre[s8] = (seg < NWG_A)
        ? __builtin_nontemporal_load(coarse + ((size_t)seg * NB + b) * CAPW + lane)
        : 0ull;
  }
  uint64_t tl[8];
#pragma unroll
  for (int s8 = 0; s8 < 8; ++s8) {
    int seg = team + (s8 << 5);
    tl[s8] = (lenv[s8] > 16u && (uint32_t)(lane + 16) < lenv[s8])
        ? __builtin_nontemporal_load(coarse + ((size_t)seg * NB + b) * CAPW + 16 + lane)
        : 0ull;
  }

#define RANK(p)                                                              \
  {                                                                          \
    uint32_t r = (uint32_t)((p) >> 48);                                      \
    uint32_t rl = r & (BROWS - 1);                                           \
    uint32_t idx = atomicAdd(&cnt[rl], 1u);                                  \
    if (idx < CAP) {                                                         \
      uint32_t c = (uint32_t)((p) >> 32) & 0xFFFFu;                          \
      pay[rl * CAP + idx] = (c << 16) | f2bf((uint32_t)(p));                 \
    } else {                                                                 \
      uint32_t oi = atomicAdd(&ovfc, 1u);                                    \
      if (oi < OVF_PB) ovfB[(size_t)b * OVF_PB + oi] = (p);                  \
    }                                                                        \
  }

#pragma unroll
  for (int s8 = 0; s8 < 8; ++s8) {
    if ((uint32_t)lane < lenv[s8]) RANK(pre[s8]);
  }
#pragma unroll
  for (int s8 = 0; s8 < 8; ++s8) {
    if (lenv[s8] > 16u && (uint32_t)(lane + 16) < lenv[s8]) RANK(tl[s8]);
  }
  // rare tail: len > 32 (+4.5 sigma)
#pragma unroll
  for (int s8 = 0; s8 < 8; ++s8) {
    uint32_t len = lenv[s8];
    if (len > 32u) {
      int seg = team + (s8 << 5);
      const uint64_t* cseg = coarse + ((size_t)seg * NB + b) * CAPW;
      for (uint32_t li = 32u + (uint32_t)lane; li < len; li += 16) {
        uint64_t p = __builtin_nontemporal_load(cseg + li);
        RANK(p);
      }
    }
  }
#undef RANK
  __syncthreads();
  if (tid == 0) ovfcB[b] = min(ovfc, (uint32_t)OVF_PB);

  // ---- gather phase ----
  const uint4* x4 = (const uint4*)xb;     // row stride: 16 uint4 (128 bf16)
  const int r0 = b << RSHIFT;

#define GSTEP(ww)                                                            \
  {                                                                          \
    uint32_t cc = (ww) >> 16;                                                \
    float vv = __uint_as_float((ww) << 16);                                  \
    uint4 a = x4[(size_t)cc * 16 + lane];                                    \
    acc0 += vv * __uint_as_float(a.x << 16);                                 \
    acc1 += vv * __uint_as_float(a.x & 0xffff0000u);                         \
    acc2 += vv * __uint_as_float(a.y << 16);                                 \
    acc3 += vv * __uint_as_float(a.y & 0xffff0000u);                         \
    acc4 += vv * __uint_as_float(a.z << 16);                                 \
    acc5 += vv * __uint_as_float(a.z & 0xffff0000u);                         \
    acc6 += vv * __uint_as_float(a.w << 16);                                 \
    acc7 += vv * __uint_as_float(a.w & 0xffff0000u);                         \
  }

  for (int rl = team; rl < BROWS; rl += 32) {
    int r = r0 + rl;
    if (r >= N_NODES) continue;
    uint32_t n = (min(cnt[rl], (uint32_t)CAP) + 7u) & ~7u;  // pads are zeros
    const uint32_t* prow = &pay[rl * CAP];
    float acc0 = 0.f, acc1 = 0.f, acc2 = 0.f, acc3 = 0.f;
    float acc4 = 0.f, acc5 = 0.f, acc6 = 0.f, acc7 = 0.f;
    for (uint32_t j = 0; j < n; j += 8) {
      // 8 wave-uniform LDS broadcast reads, then 8 x-row loads in flight
      uint32_t w0 = prow[j + 0];
      uint32_t w1 = prow[j + 1];
      uint32_t w2 = prow[j + 2];
      uint32_t w3 = prow[j + 3];
      uint32_t w4 = prow[j + 4];
      uint32_t w5 = prow[j + 5];
      uint32_t w6 = prow[j + 6];
      uint32_t w7 = prow[j + 7];
      GSTEP(w0) GSTEP(w1) GSTEP(w2) GSTEP(w3)
      GSTEP(w4) GSTEP(w5) GSTEP(w6) GSTEP(w7)
    }
    f4v lo, hi;
    lo.x = acc0; lo.y = acc1; lo.z = acc2; lo.w = acc3;
    hi.x = acc4; hi.y = acc5; hi.z = acc6; hi.w = acc7;
    f4v* o = (f4v*)out + (size_t)r * 32 + lane * 2;
    __builtin_nontemporal_store(lo, o);
    __builtin_nontemporal_store(hi, o + 1);
  }
#undef GSTEP
}

// exact cleanup for packed (row,col,f32val) overflow entries. Early-exits when
// all 641 region counts are zero (the expected case).
__global__ void __launch_bounds__(256) ovf_pack_kernel(const float* __restrict__ x,
                                                       const uint32_t* __restrict__ ovfcA,
                                                       const uint64_t* __restrict__ ovfA,
                                                       const uint32_t* __restrict__ ovfcB,
                                                       const uint64_t* __restrict__ ovfB,
                                                       float* __restrict__ out) {
  __shared__ int any;
  if (threadIdx.x == 0) any = 0;
  __syncthreads();
  for (int t = threadIdx.x; t < NREG; t += 256) {
    uint32_t c = (t < NWG_A) ? ovfcA[t] : ovfcB[t - NWG_A];
    if (c) any = 1;
  }
  __syncthreads();
  if (!any) return;

  int group = (int)((blockIdx.x * 256 + threadIdx.x) >> 7);
  int f = threadIdx.x & 127;
  const int ngroups = (16 * 256) >> 7;  // 32 groups
  for (int reg = group; reg < NREG; reg += ngroups) {
    uint32_t c;
    const uint64_t* basep;
    if (reg < NWG_A) {
      c = min(ovfcA[reg], (uint32_t)OVF_PW);
      basep = ovfA + (size_t)reg * OVF_PW;
    } else {
      c = min(ovfcB[reg - NWG_A], (uint32_t)OVF_PB);
      basep = ovfB + (size_t)(reg - NWG_A) * OVF_PB;
    }
    for (uint32_t i = 0; i < c; ++i) {
      uint64_t p = basep[i];
      uint32_t r = (uint32_t)(p >> 48);
      uint32_t cc = (uint32_t)((p >> 32) & 0xFFFFu);
      float v = __uint_as_float((uint32_t)p);
      atomicAdd(&out[(size_t)r * N_FEAT + f], v * x[(size_t)cc * N_FEAT + f]);
    }
  }
}

// =================== FALLBACK: fused atomic scatter ============================

__global__ void __launch_bounds__(256) scatter_fused_kernel(const float* __restrict__ x,
                                                            const float* __restrict__ adj_vals,
                                                            const int* __restrict__ row,
                                                            const int* __restrict__ col,
                                                            float* __restrict__ out) {
  long long t = (long long)blockIdx.x * blockDim.x + threadIdx.x;
  int e = (int)(t >> 6);
  int lane = (int)(t & 63);
  if (e >= N_EDGES) return;
  if (!edge_keep((uint32_t)e)) return;
  float v = adj_vals[e] / 0.9f;
  float2 xf = *(const float2*)(x + (long long)col[e] * N_FEAT + lane * 2);
  float* dst = out + (long long)row[e] * N_FEAT + lane * 2;
  atomicAdd(dst, v * xf.x);
  atomicAdd(dst + 1, v * xf.y);
}

// ---------------- launch --------------------------------------------------------

extern "C" void kernel_launch(void* const* d_in, const int* in_sizes, int n_in,
                              void* d_out, int out_size, void* d_ws, size_t ws_size,
                              hipStream_t stream) {
  const float* x        = (const float*)d_in[0];
  const float* adj_vals = (const float*)d_in[1];
  const int*   row      = (const int*)d_in[2];
  const int*   col      = (const int*)d_in[3];
  float* out = (float*)d_out;

  // ---- workspace layout (nothing needs host-side init) ----
  size_t a_ovfcA   = 0;                                                    // NWG_A u32
  size_t a_ovfcB   = (a_ovfcA + (size_t)NWG_A * 4 + 255) & ~255ull;        // NB u32
  size_t a_lens    = (a_ovfcB + (size_t)NB * 4 + 255) & ~255ull;           // NB*NWG_A u32
  size_t a_ovfA    = (a_lens + (size_t)NB * NWG_A * 4 + 255) & ~255ull;    // NWG_A*OVF_PW u64
  size_t a_ovfB    = (a_ovfA + (size_t)NWG_A * OVF_PW * 8 + 255) & ~255ull; // NB*OVF_PB u64
  size_t a_coarse  = (a_ovfB + (size_t)NB * OVF_PB * 8 + 255) & ~255ull;   // NWG_A*NB*CAPW u64
  size_t a_xb      = (a_coarse + (size_t)NWG_A * NB * CAPW * 8 + 255) & ~255ull;  // N*F bf16
  size_t need      = a_xb + (size_t)N_NODES * N_FEAT * 2;

  if (ws_size >= need) {
    uint32_t* ovfcA   = (uint32_t*)((char*)d_ws + a_ovfcA);
    uint32_t* ovfcB   = (uint32_t*)((char*)d_ws + a_ovfcB);
    uint32_t* lens    = (uint32_t*)((char*)d_ws + a_lens);
    uint64_t* ovfA    = (uint64_t*)((char*)d_ws + a_ovfA);
    uint64_t* ovfB    = (uint64_t*)((char*)d_ws + a_ovfB);
    uint64_t* coarse  = (uint64_t*)((char*)d_ws + a_coarse);
    uint32_t* xb      = (uint32_t*)((char*)d_ws + a_xb);

    convA_kernel<<<NWG_A, A_THREADS, 0, stream>>>(x, xb, adj_vals, row, col,
                                                  coarse, lens, ovfcA, ovfA);
    rank_gather_kernel<<<NB, 512, 0, stream>>>(xb, coarse, lens, ovfcB, ovfB, out);
    ovf_pack_kernel<<<16, 256, 0, stream>>>(x, ovfcA, ovfA, ovfcB, ovfB, out);
  } else {
    hipMemsetAsync(d_out, 0, (size_t)out_size * sizeof(float), stream);
    long long total_threads = (long long)N_EDGES * 64;
    scatter_fused_kernel<<<(int)((total_threads + 255) / 256), 256, 0, stream>>>(
        x, adj_vals, row, col, out);
  }
}